// Round 5
// baseline (19.782 us; speedup 1.0000x reference)
//
#include <hip/hip_runtime.h>
#include <hip/hip_bf16.h>

// Problem constants (fixed by the reference)
#define NG   1024
#define NC   64
#define CULL_T 15.0f   // cull when sigma > T; dropped mass <= 1024*2*0.07*e^-15 ~ 4e-5
#define MAXL 256       // compacted live-gaussian capacity (uniform data: max ~45/tile)
#define MAXC 128       // feats chunk rows per pass (typ. 1 pass)

// ---------------------------------------------------------------------------
// Single fused kernel: one 1024-thread block (16 waves = 4 waves/SIMD) per
// 32x8 pixel tile.
//  Phase A: thread t preps gaussian t (tanh/divides/exp) in registers, culls
//           vs tile, ballot-compacts (ascending ids -> deterministic sum
//           order), writes surviving params compacted into LDS.
//  Phase A2: softplus(features) for live gaussians only -> LDS.
//  Phase B: per-pixel accumulation, 4-way channel split (16 ch/thread).
//           All inner-loop LDS reads are position-indexed (loop-static
//           addresses), A/B register-pipelined one iteration ahead.
// ---------------------------------------------------------------------------
__global__ __launch_bounds__(1024, 4) void fused_render_kernel(
    const float* __restrict__ xyz,  const float* __restrict__ chol,
    const float* __restrict__ opac, const float* __restrict__ fdc,
    const float* __restrict__ gfrq, const float* __restrict__ gwts,
    float* __restrict__ out)
{
    __shared__ float4 s_p0[MAXL];              // (xs, ys, ca, cb)
    __shared__ float4 s_p1[MAXL];              // (cc, oK, wk0, wk1)
    __shared__ float4 s_p2[MAXL];              // (f00, f01, f10, f11)
    __shared__ unsigned short s_list[MAXL];    // gaussian id per list pos
    __shared__ float  s_feat[MAXC][NC];        // 32KB
    __shared__ int    s_scnt[16];              // per-wave live counts

    const int tid  = threadIdx.x;
    const int lane = tid & 63, w = tid >> 6;   // 16 waves

    const int x0 = (blockIdx.x & 7) << 5;   // 8 tiles across (32 px wide)
    const int y0 = (blockIdx.x >> 3) << 3;  // 32 tiles down  (8 px tall)
    const float xlo = x0 + 0.5f, xhi = x0 + 31.5f;
    const float ylo = y0 + 0.5f, yhi = y0 + 7.5f;

    // ---- Phase A: prep + cull (1 gaussian per thread) -------------------
    {
        const int n = tid;
        const float2 xy = ((const float2*)xyz)[n];
        const float xs = 128.f * (tanhf(xy.x) + 1.f);
        const float ys = 128.f * (tanhf(xy.y) + 1.f);

        const float l1 = chol[3*n]     + 0.5f;
        const float l2 = chol[3*n + 1];
        const float l3 = chol[3*n + 2] + 0.5f;
        const float s11 = l1*l1, s12 = l1*l2, s22 = l2*l2 + l3*l3;
        const float dt  = (l1*l3) * (l1*l3);
        const float ca = s22/dt, cb = -(s12/dt), cc = s11/dt;
        const float mid = 0.5f*(s11 + s22);
        const float lam = mid + sqrtf(fmaxf(mid*mid - dt, 1e-8f));
        const float radius = ceilf(3.f * sqrtf(lam));
        const float keep = (radius > 1.0f) ? 1.f : 0.f;   // RADIUS_CLIP = 1.0
        const float oK = opac[n] * keep;
        const float r2 = (oK != 0.f) ? (2.f * CULL_T * lam) : -1.f;

        // point-in-rounded-rect cull against this tile
        const float nx = fminf(fmaxf(xs, xlo), xhi);
        const float ny = fminf(fmaxf(ys, ylo), yhi);
        const float ddx = xs - nx, ddy = ys - ny;
        const bool live = (ddx*ddx + ddy*ddy) <= r2;

        const unsigned long long m = __ballot(live);
        const int pos = __popcll(m & ((1ull << lane) - 1ull));
        if (lane == 0) s_scnt[w] = __popcll(m);
        __syncthreads();

        int off = 0, tot = 0;
        #pragma unroll
        for (int k = 0; k < 16; ++k) {
            const int c = s_scnt[k];
            if (k < w) off += c;
            tot += c;
        }
        if (live) {
            const int p = off + pos;
            if (p < MAXL) {
                s_list[p] = (unsigned short)n;
                const float4 gf = ((const float4*)gfrq)[n];
                const float2 gw = ((const float2*)gwts)[n];
                s_p0[p] = make_float4(xs, ys, ca, cb);
                s_p1[p] = make_float4(cc, oK, 1.f/(1.f + __expf(-gw.x)),
                                              1.f/(1.f + __expf(-gw.y)));
                s_p2[p] = make_float4(__expf(gf.x), __expf(gf.y),
                                      __expf(gf.z), __expf(gf.w));
            }
        }
        __syncthreads();
        s_scnt[0] = min(tot, MAXL);   // broadcast total (uniform anyway)
    }
    const int total = s_scnt[0];

    // ---- Phase B: per-pixel accumulation, 4-way channel split -----------
    const int pid = tid & 255;               // pixel within tile
    const int c0  = (tid >> 8) << 4;         // channel quarter: 0,16,32,48
    const int tx  = pid & 31, ty = pid >> 5;
    const float px = x0 + tx + 0.5f;
    const float py = y0 + ty + 0.5f;

    float acc[16];
    #pragma unroll
    for (int c = 0; c < 16; ++c) acc[c] = 0.f;

    // named A/B pipeline regs (static indexing only — rule #20)
    float4 A_p0, A_p1, A_p2, A_f0, A_f1, A_f2, A_f3;
    float4 B_p0, B_p1, B_p2, B_f0, B_f1, B_f2, B_f3;

    for (int base = 0; base < total; base += MAXC) {
        const int clen = min(total - base, MAXC);

        // softplus(features) for this chunk's live gaussians -> LDS
        for (int v = tid; v < (clen << 6); v += 1024) {
            const int j = v >> 6, c = v & 63;
            const int n = (int)s_list[base + j];
            const float x = fdc[(n << 6) + c];
            const float mx = fmaxf(x, 0.f);           // stable softplus
            s_feat[j][c] = mx + __logf(__expf(x - mx) + __expf(-mx));
        }
        __syncthreads();

#define LOADG(P, i) do {                                                     \
        P##_p0 = s_p0[base + (i)]; P##_p1 = s_p1[base + (i)];                \
        P##_p2 = s_p2[base + (i)];                                           \
        const float4* fl = (const float4*)(&s_feat[i][c0]);                  \
        P##_f0 = fl[0]; P##_f1 = fl[1]; P##_f2 = fl[2]; P##_f3 = fl[3];      \
    } while (0)

#define COMPUTE(P) do {                                                      \
        const float dx = P##_p0.x - px, dy = P##_p0.y - py;                  \
        const float sig = 0.5f*(P##_p0.z*dx*dx + P##_p1.x*dy*dy)             \
                        + P##_p0.w*dx*dy;                                    \
        const float a = __expf(-sig) * P##_p1.y;                             \
        const float mfac = 1.f + P##_p1.z*__cosf(P##_p2.x*dx + P##_p2.y*dy)  \
                               + P##_p1.w*__cosf(P##_p2.z*dx + P##_p2.w*dy); \
        const float wgt = a * mfac;                                          \
        acc[ 0] = fmaf(wgt, P##_f0.x, acc[ 0]);                              \
        acc[ 1] = fmaf(wgt, P##_f0.y, acc[ 1]);                              \
        acc[ 2] = fmaf(wgt, P##_f0.z, acc[ 2]);                              \
        acc[ 3] = fmaf(wgt, P##_f0.w, acc[ 3]);                              \
        acc[ 4] = fmaf(wgt, P##_f1.x, acc[ 4]);                              \
        acc[ 5] = fmaf(wgt, P##_f1.y, acc[ 5]);                              \
        acc[ 6] = fmaf(wgt, P##_f1.z, acc[ 6]);                              \
        acc[ 7] = fmaf(wgt, P##_f1.w, acc[ 7]);                              \
        acc[ 8] = fmaf(wgt, P##_f2.x, acc[ 8]);                              \
        acc[ 9] = fmaf(wgt, P##_f2.y, acc[ 9]);                              \
        acc[10] = fmaf(wgt, P##_f2.z, acc[10]);                              \
        acc[11] = fmaf(wgt, P##_f2.w, acc[11]);                              \
        acc[12] = fmaf(wgt, P##_f3.x, acc[12]);                              \
        acc[13] = fmaf(wgt, P##_f3.y, acc[13]);                              \
        acc[14] = fmaf(wgt, P##_f3.z, acc[14]);                              \
        acc[15] = fmaf(wgt, P##_f3.w, acc[15]);                              \
    } while (0)

        if (clen > 0) {
            LOADG(A, 0);
            int i = 0;
            while (true) {
                bool hasN = (i + 1) < clen;
                if (hasN) LOADG(B, i + 1);
                COMPUTE(A);
                ++i;
                if (!hasN) break;
                hasN = (i + 1) < clen;
                if (hasN) LOADG(A, i + 1);
                COMPUTE(B);
                ++i;
                if (!hasN) break;
            }
        }
#undef LOADG
#undef COMPUTE
        __syncthreads();
    }

    // store: out[(c, y, x)]; per store instr: 2x128B contiguous segments
    const int p = ((y0 + ty) << 8) + x0 + tx;
    #pragma unroll
    for (int c = 0; c < 16; ++c)
        out[((c0 + c) << 16) + p] = fminf(fmaxf(acc[c], 0.f), 1.f);
}

// ---------------------------------------------------------------------------
extern "C" void kernel_launch(void* const* d_in, const int* in_sizes, int n_in,
                              void* d_out, int out_size, void* d_ws, size_t ws_size,
                              hipStream_t stream) {
    const float* xyz  = (const float*)d_in[0];
    const float* chol = (const float*)d_in[1];
    const float* opac = (const float*)d_in[2];
    const float* fdc  = (const float*)d_in[3];
    const float* gfrq = (const float*)d_in[4];
    const float* gwts = (const float*)d_in[5];

    fused_render_kernel<<<256, 1024, 0, stream>>>(xyz, chol, opac, fdc,
                                                  gfrq, gwts, (float*)d_out);
}

// Round 6
// 18.818 us; speedup vs baseline: 1.0512x; 1.0512x over previous
//
#include <hip/hip_runtime.h>
#include <hip/hip_bf16.h>

// Problem constants (fixed by the reference)
#define NG     1024
#define NC     64
#define CULL_T 15.0f   // cull when sigma > T; dropped mass <= ~4e-5
#define MAXL   256     // compacted live capacity (observed max ~45/tile)
#define KPAD   72      // padded K row length (f16) -> 144B rows, spreads banks
#define L2E    1.44269504f
#define INV2PI 0.15915494f

typedef float    f32x4 __attribute__((ext_vector_type(4)));
typedef _Float16 f16x4 __attribute__((ext_vector_type(4)));
typedef _Float16 f16x2 __attribute__((ext_vector_type(2)));

// wgt for one (gaussian, pixel) pair. Coeffs pre-folded:
//  p0 = (xs, ys, na, nb), p1 = (nc, oK, wk0, wk1), p2 = rev-freqs (f/2pi)
//  exp2 arg = na*dx^2 + nb*dx*dy + nc*dy^2  (log2e and -0.5 folded in)
__device__ __forceinline__ float wgt_f(float4 p0, float4 p1, float4 p2,
                                       float pxf, float pyf) {
    const float dx = p0.x - pxf, dy = p0.y - pyf;
    const float t  = fmaf(p0.w, dy, p0.z * dx);
    const float s2 = fmaf(p1.x * dy, dy, dx * t);
    const float e  = __builtin_amdgcn_exp2f(s2);
    const float r1 = fmaf(p2.x, dx, p2.y * dy);
    const float c1 = __builtin_amdgcn_cosf(__builtin_amdgcn_fractf(r1));
    const float r2 = fmaf(p2.z, dx, p2.w * dy);
    const float c2 = __builtin_amdgcn_cosf(__builtin_amdgcn_fractf(r2));
    const float m  = fmaf(p1.w, c2, fmaf(p1.z, c1, 1.f));
    return e * p1.y * m;
}

// ---------------------------------------------------------------------------
// One 256-thread block (4 waves) per 32x8 pixel tile.
//  Phase A: prep 4 gaussians/thread in regs, cull, ballot-compact (ascending
//           ids -> deterministic), params -> LDS; zero tail slots.
//  Per 64-K chunk:
//    A-stage: softplus(feats)^T -> A_lds[c][k] (f16, zero-padded)
//    B-stage: wgt(k, px) -> B_lds[px][k] (f16, waves parallel over k)
//    MFMA:    D[ch][px] += A x B, v_mfma_f32_16x16x16f16, 4x4 C-tiles/wave
//  Store: C/D frags (col=px=lane&15, row=ch=(lane>>4)*4+q) -> out[(c,y,x)].
// ---------------------------------------------------------------------------
__global__ __launch_bounds__(256) void fused_mfma_kernel(
    const float* __restrict__ xyz,  const float* __restrict__ chol,
    const float* __restrict__ opac, const float* __restrict__ fdc,
    const float* __restrict__ gfrq, const float* __restrict__ gwts,
    float* __restrict__ out)
{
    __shared__ float4 s_p0[MAXL], s_p1[MAXL], s_p2[MAXL];
    __shared__ unsigned short s_list[MAXL];
    __shared__ int s_scnt[16];
    __shared__ _Float16 A_lds[NC][KPAD];     //  9.2 KB  feats^T
    __shared__ _Float16 B_lds[256][KPAD];    // 36.9 KB  wgt

    const int tid  = threadIdx.x;
    const int lane = tid & 63, w = tid >> 6;

    const int x0 = (blockIdx.x & 7) << 5;
    const int y0 = (blockIdx.x >> 3) << 3;
    const float xlo = x0 + 0.5f, xhi = x0 + 31.5f;
    const float ylo = y0 + 0.5f, yhi = y0 + 7.5f;

    // ---- Phase A: prep + cull, 4 gaussians per thread -------------------
    float4 P0[4], P1[4], P2[4];
    bool   lv[4];
    int    pos[4];
    #pragma unroll
    for (int r = 0; r < 4; ++r) {
        const int n = (r << 8) + tid;        // r-major => ascending ids
        const float2 xy = ((const float2*)xyz)[n];
        const float xs = 128.f * (tanhf(xy.x) + 1.f);
        const float ys = 128.f * (tanhf(xy.y) + 1.f);

        const float l1 = chol[3*n]     + 0.5f;
        const float l2 = chol[3*n + 1];
        const float l3 = chol[3*n + 2] + 0.5f;
        const float s11 = l1*l1, s12 = l1*l2, s22 = l2*l2 + l3*l3;
        const float dt  = (l1*l3) * (l1*l3);
        const float inv = 1.f / dt;
        const float na = -0.5f * L2E * s22 * inv;   // folded: -0.5*ca*log2e
        const float nb =          L2E * s12 * inv;  // folded: -cb*log2e
        const float nc = -0.5f * L2E * s11 * inv;
        const float mid = 0.5f * (s11 + s22);
        const float lam = mid + sqrtf(fmaxf(mid*mid - dt, 1e-8f));
        const float radius = ceilf(3.f * sqrtf(lam));
        const float keep = (radius > 1.0f) ? 1.f : 0.f;
        const float oK = opac[n] * keep;
        const float r2 = (oK != 0.f) ? (2.f * CULL_T * lam) : -1.f;

        const float nx = fminf(fmaxf(xs, xlo), xhi);
        const float ny = fminf(fmaxf(ys, ylo), yhi);
        const float ddx = xs - nx, ddy = ys - ny;
        lv[r] = (ddx*ddx + ddy*ddy) <= r2;

        const unsigned long long m = __ballot(lv[r]);
        pos[r] = __popcll(m & ((1ull << lane) - 1ull));
        if (lane == 0) s_scnt[(r << 2) + w] = __popcll(m);

        const float4 gf = ((const float4*)gfrq)[n];
        const float2 gw = ((const float2*)gwts)[n];
        P0[r] = make_float4(xs, ys, na, nb);
        P1[r] = make_float4(nc, oK, 1.f/(1.f + __expf(-gw.x)),
                                    1.f/(1.f + __expf(-gw.y)));
        P2[r] = make_float4(__expf(gf.x)*INV2PI, __expf(gf.y)*INV2PI,
                            __expf(gf.z)*INV2PI, __expf(gf.w)*INV2PI);
    }
    __syncthreads();

    // prefix over the 16 (r, wave) segments -> ascending ids
    int pre[17];
    pre[0] = 0;
    #pragma unroll
    for (int s = 0; s < 16; ++s) pre[s+1] = pre[s] + s_scnt[s];
    const int total = min(pre[16], MAXL);

    #pragma unroll
    for (int r = 0; r < 4; ++r) {
        if (lv[r]) {
            const int p = pre[(r << 2) + w] + pos[r];
            if (p < MAXL) {
                s_list[p] = (unsigned short)((r << 8) + tid);
                s_p0[p] = P0[r]; s_p1[p] = P1[r]; s_p2[p] = P2[r];
            }
        }
    }
    // zero tail param slots => padded k produce wgt = e*0*1 = 0
    for (int idx = total + tid; idx < MAXL; idx += 256) {
        s_p0[idx] = make_float4(0,0,0,0);
        s_p1[idx] = make_float4(0,0,0,0);
        s_p2[idx] = make_float4(0,0,0,0);
    }
    __syncthreads();

    // ---- Per-chunk: stage A (feats) + B (wgt), then MFMA ----------------
    const int c15 = lane & 15, g = lane >> 4;

    f32x4 acc[4][4];   // [mt][ntl], static indexing only
    #pragma unroll
    for (int a = 0; a < 4; ++a)
        #pragma unroll
        for (int b = 0; b < 4; ++b)
            acc[a][b] = (f32x4){0.f, 0.f, 0.f, 0.f};

    float pxf[4], pyf[4];
    #pragma unroll
    for (int j = 0; j < 4; ++j) {
        const int px = j*64 + lane;
        pxf[j] = x0 + (px & 31) + 0.5f;
        pyf[j] = y0 + (px >> 5) + 0.5f;
    }

    for (int base = 0; base < total; base += 64) {
        const int rem = min(total - base, 64);

        // A-stage: A_lds[c][k] = softplus(fdc[list[k]][c]) as f16
        {
            const int c = tid & 63, kq = tid >> 6;
            #pragma unroll
            for (int i = 0; i < 8; ++i) {
                const int k0 = i*8 + kq*2;
                float v0 = 0.f, v1 = 0.f;
                if (k0 < rem) {
                    const int n = (int)s_list[base + k0];
                    const float x = fdc[(n << 6) + c];
                    v0 = 0.69314718f * __builtin_amdgcn_logf(
                             1.f + __builtin_amdgcn_exp2f(L2E * x));
                }
                if (k0 + 1 < rem) {
                    const int n = (int)s_list[base + k0 + 1];
                    const float x = fdc[(n << 6) + c];
                    v1 = 0.69314718f * __builtin_amdgcn_logf(
                             1.f + __builtin_amdgcn_exp2f(L2E * x));
                }
                *(f16x2*)&A_lds[c][k0] = (f16x2){(_Float16)v0, (_Float16)v1};
            }
        }

        // B-stage: waves parallel over k; each wave: k = 2*(4i+w)+{0,1}
        #pragma unroll
        for (int i = 0; i < 8; ++i) {
            const int k0 = 2*(i*4 + w);
            const float4 p0a = s_p0[base+k0],   p1a = s_p1[base+k0],   p2a = s_p2[base+k0];
            const float4 p0b = s_p0[base+k0+1], p1b = s_p1[base+k0+1], p2b = s_p2[base+k0+1];
            #pragma unroll
            for (int j = 0; j < 4; ++j) {
                const float w0 = wgt_f(p0a, p1a, p2a, pxf[j], pyf[j]);
                const float w1 = wgt_f(p0b, p1b, p2b, pxf[j], pyf[j]);
                const int px = j*64 + lane;
                *(f16x2*)&B_lds[px][k0] = (f16x2){(_Float16)w0, (_Float16)w1};
            }
        }
        __syncthreads();

        // MFMA: wave w owns n-tiles {4w..4w+3}, all 4 m-tiles (ch)
        #pragma unroll
        for (int kc = 0; kc < 4; ++kc) {
            const int kb = kc*16 + g*4;
            f16x4 af0 = *(const f16x4*)&A_lds[ 0 + c15][kb];
            f16x4 af1 = *(const f16x4*)&A_lds[16 + c15][kb];
            f16x4 af2 = *(const f16x4*)&A_lds[32 + c15][kb];
            f16x4 af3 = *(const f16x4*)&A_lds[48 + c15][kb];
            f16x4 bf0 = *(const f16x4*)&B_lds[(w*4+0)*16 + c15][kb];
            f16x4 bf1 = *(const f16x4*)&B_lds[(w*4+1)*16 + c15][kb];
            f16x4 bf2 = *(const f16x4*)&B_lds[(w*4+2)*16 + c15][kb];
            f16x4 bf3 = *(const f16x4*)&B_lds[(w*4+3)*16 + c15][kb];

            acc[0][0] = __builtin_amdgcn_mfma_f32_16x16x16f16(af0, bf0, acc[0][0], 0,0,0);
            acc[0][1] = __builtin_amdgcn_mfma_f32_16x16x16f16(af0, bf1, acc[0][1], 0,0,0);
            acc[0][2] = __builtin_amdgcn_mfma_f32_16x16x16f16(af0, bf2, acc[0][2], 0,0,0);
            acc[0][3] = __builtin_amdgcn_mfma_f32_16x16x16f16(af0, bf3, acc[0][3], 0,0,0);
            acc[1][0] = __builtin_amdgcn_mfma_f32_16x16x16f16(af1, bf0, acc[1][0], 0,0,0);
            acc[1][1] = __builtin_amdgcn_mfma_f32_16x16x16f16(af1, bf1, acc[1][1], 0,0,0);
            acc[1][2] = __builtin_amdgcn_mfma_f32_16x16x16f16(af1, bf2, acc[1][2], 0,0,0);
            acc[1][3] = __builtin_amdgcn_mfma_f32_16x16x16f16(af1, bf3, acc[1][3], 0,0,0);
            acc[2][0] = __builtin_amdgcn_mfma_f32_16x16x16f16(af2, bf0, acc[2][0], 0,0,0);
            acc[2][1] = __builtin_amdgcn_mfma_f32_16x16x16f16(af2, bf1, acc[2][1], 0,0,0);
            acc[2][2] = __builtin_amdgcn_mfma_f32_16x16x16f16(af2, bf2, acc[2][2], 0,0,0);
            acc[2][3] = __builtin_amdgcn_mfma_f32_16x16x16f16(af2, bf3, acc[2][3], 0,0,0);
            acc[3][0] = __builtin_amdgcn_mfma_f32_16x16x16f16(af3, bf0, acc[3][0], 0,0,0);
            acc[3][1] = __builtin_amdgcn_mfma_f32_16x16x16f16(af3, bf1, acc[3][1], 0,0,0);
            acc[3][2] = __builtin_amdgcn_mfma_f32_16x16x16f16(af3, bf2, acc[3][2], 0,0,0);
            acc[3][3] = __builtin_amdgcn_mfma_f32_16x16x16f16(af3, bf3, acc[3][3], 0,0,0);
        }
        __syncthreads();   // protect LDS before next chunk's staging
    }

    // ---- Store: D frag (col=px: lane&15, row=ch: g*4+q), clipped ---------
    #pragma unroll
    for (int mt = 0; mt < 4; ++mt) {
        #pragma unroll
        for (int ntl = 0; ntl < 4; ++ntl) {
            const int px = (w*4 + ntl)*16 + c15;
            const int pg = ((y0 + (px >> 5)) << 8) + x0 + (px & 31);
            #pragma unroll
            for (int q = 0; q < 4; ++q) {
                const int ch = mt*16 + g*4 + q;
                out[(ch << 16) + pg] = fminf(fmaxf(acc[mt][ntl][q], 0.f), 1.f);
            }
        }
    }
}

// ---------------------------------------------------------------------------
extern "C" void kernel_launch(void* const* d_in, const int* in_sizes, int n_in,
                              void* d_out, int out_size, void* d_ws, size_t ws_size,
                              hipStream_t stream) {
    const float* xyz  = (const float*)d_in[0];
    const float* chol = (const float*)d_in[1];
    const float* opac = (const float*)d_in[2];
    const float* fdc  = (const float*)d_in[3];
    const float* gfrq = (const float*)d_in[4];
    const float* gwts = (const float*)d_in[5];

    fused_mfma_kernel<<<256, 256, 0, stream>>>(xyz, chol, opac, fdc,
                                               gfrq, gwts, (float*)d_out);
}

// Round 7
// 12.938 us; speedup vs baseline: 1.5290x; 1.4545x over previous
//
#include <hip/hip_runtime.h>
#include <hip/hip_bf16.h>

// Problem constants (fixed by the reference)
#define NG     1024
#define NC     64
#define CULL_T 15.0f   // cull when sigma > T; dropped mass <= ~4e-5
#define MAXL   256     // compacted live capacity (observed max ~45/tile)
#define KPAD   72      // padded K row length (f16) -> 144B rows, spreads banks
#define L2E    1.44269504f
#define INV2PI 0.15915494f

typedef float    f32x4 __attribute__((ext_vector_type(4)));
typedef _Float16 f16x4 __attribute__((ext_vector_type(4)));
typedef _Float16 f16x2 __attribute__((ext_vector_type(2)));

// wgt for one (gaussian, pixel) pair. Coeffs pre-folded:
//  p0 = (xs, ys, na, nb), p1 = (nc, oK, wk0, wk1), p2 = freqs/2pi
//  exp2 arg = na*dx^2 + nb*dx*dy + nc*dy^2  (log2e and -0.5 folded in)
__device__ __forceinline__ float wgt_f(float4 p0, float4 p1, float4 p2,
                                       float pxf, float pyf) {
    const float dx = p0.x - pxf, dy = p0.y - pyf;
    const float t  = fmaf(p0.w, dy, p0.z * dx);
    const float s2 = fmaf(p1.x * dy, dy, dx * t);
    const float e  = __builtin_amdgcn_exp2f(s2);
    const float r1 = fmaf(p2.x, dx, p2.y * dy);
    const float c1 = __builtin_amdgcn_cosf(__builtin_amdgcn_fractf(r1));
    const float r2 = fmaf(p2.z, dx, p2.w * dy);
    const float c2 = __builtin_amdgcn_cosf(__builtin_amdgcn_fractf(r2));
    const float m  = fmaf(p1.w, c2, fmaf(p1.z, c1, 1.f));
    return e * p1.y * m;
}

// ---------------------------------------------------------------------------
// One 512-thread block (8 waves, 2/SIMD) per 32x8 pixel tile.
//  Phase A: prep 2 gaussians/thread (all-HW-op math: exp2/rcp/sqrt), cull,
//           ballot-compact ascending -> LDS params; zero tail slots.
//  Per 64-K chunk (rem-bounded to ceil(rem/16)*16 slots):
//    A-stage: softplus(feats)^T -> A_lds[c][k] (f16, zero-padded)
//    B-stage: wgt(k, px) -> B_lds[px][k] (f16; waves parallel over k)
//    MFMA:    v_mfma_f32_16x16x16f16; wave owns 2 px-tiles x 4 ch-tiles
//  Store: D frags (col=px=lane&15, row=ch=(lane>>4)*4+q) -> out[(c,y,x)].
// ---------------------------------------------------------------------------
__global__ __launch_bounds__(512) void fused_mfma_kernel(
    const float* __restrict__ xyz,  const float* __restrict__ chol,
    const float* __restrict__ opac, const float* __restrict__ fdc,
    const float* __restrict__ gfrq, const float* __restrict__ gwts,
    float* __restrict__ out)
{
    __shared__ float4 s_p0[MAXL], s_p1[MAXL], s_p2[MAXL];
    __shared__ unsigned short s_list[MAXL];
    __shared__ int s_scnt[16];
    __shared__ _Float16 A_lds[NC][KPAD];     //  9.2 KB  feats^T
    __shared__ _Float16 B_lds[256][KPAD];    // 36.9 KB  wgt

    const int tid  = threadIdx.x;
    const int lane = tid & 63, w = tid >> 6;   // 8 waves

    const int x0 = (blockIdx.x & 7) << 5;
    const int y0 = (blockIdx.x >> 3) << 3;
    const float xlo = x0 + 0.5f, xhi = x0 + 31.5f;
    const float ylo = y0 + 0.5f, yhi = y0 + 7.5f;

    // ---- Phase A: prep + cull, 2 gaussians per thread (HW-op math) ------
    float4 P0[2], P1[2], P2[2];
    bool   lv[2];
    int    pos[2];
    #pragma unroll
    for (int r = 0; r < 2; ++r) {
        const int n = (r << 9) + tid;        // r-major => ascending ids
        const float2 xy = ((const float2*)xyz)[n];
        // xs = 128*(tanh(x)+1) = 256 - 256/(1+exp2(2*log2e*x))
        const float ex = __builtin_amdgcn_exp2f(2.f * L2E * xy.x);
        const float ey = __builtin_amdgcn_exp2f(2.f * L2E * xy.y);
        const float xs = 256.f - 256.f * __builtin_amdgcn_rcpf(1.f + ex);
        const float ys = 256.f - 256.f * __builtin_amdgcn_rcpf(1.f + ey);

        const float l1 = chol[3*n]     + 0.5f;
        const float l2 = chol[3*n + 1];
        const float l3 = chol[3*n + 2] + 0.5f;
        const float s11 = l1*l1, s12 = l1*l2, s22 = l2*l2 + l3*l3;
        const float dt  = (l1*l3) * (l1*l3);
        const float inv = __builtin_amdgcn_rcpf(dt);
        const float na = -0.5f * L2E * s22 * inv;   // -0.5*ca*log2e
        const float nb =          L2E * s12 * inv;  // -cb*log2e
        const float nc = -0.5f * L2E * s11 * inv;
        const float mid = 0.5f * (s11 + s22);
        const float lam = mid + __builtin_amdgcn_sqrtf(fmaxf(mid*mid - dt, 1e-8f));
        const float radius = ceilf(3.f * __builtin_amdgcn_sqrtf(lam));
        const float keep = (radius > 1.0f) ? 1.f : 0.f;   // RADIUS_CLIP=1
        const float oK = opac[n] * keep;
        const float r2 = (oK != 0.f) ? (2.f * CULL_T * lam) : -1.f;

        const float nx = fminf(fmaxf(xs, xlo), xhi);
        const float ny = fminf(fmaxf(ys, ylo), yhi);
        const float ddx = xs - nx, ddy = ys - ny;
        lv[r] = (ddx*ddx + ddy*ddy) <= r2;

        const unsigned long long m = __ballot(lv[r]);
        pos[r] = __popcll(m & ((1ull << lane) - 1ull));
        if (lane == 0) s_scnt[(r << 3) + w] = __popcll(m);

        const float4 gf = ((const float4*)gfrq)[n];
        const float2 gw = ((const float2*)gwts)[n];
        P0[r] = make_float4(xs, ys, na, nb);
        P1[r] = make_float4(nc, oK,
            __builtin_amdgcn_rcpf(1.f + __builtin_amdgcn_exp2f(-L2E*gw.x)),
            __builtin_amdgcn_rcpf(1.f + __builtin_amdgcn_exp2f(-L2E*gw.y)));
        P2[r] = make_float4(
            __builtin_amdgcn_exp2f(L2E*gf.x)*INV2PI,
            __builtin_amdgcn_exp2f(L2E*gf.y)*INV2PI,
            __builtin_amdgcn_exp2f(L2E*gf.z)*INV2PI,
            __builtin_amdgcn_exp2f(L2E*gf.w)*INV2PI);
    }
    __syncthreads();

    int pre[17];
    pre[0] = 0;
    #pragma unroll
    for (int s = 0; s < 16; ++s) pre[s+1] = pre[s] + s_scnt[s];
    const int total = min(pre[16], MAXL);

    #pragma unroll
    for (int r = 0; r < 2; ++r) {
        if (lv[r]) {
            const int p = pre[(r << 3) + w] + pos[r];
            if (p < MAXL) {
                s_list[p] = (unsigned short)((r << 9) + tid);
                s_p0[p] = P0[r]; s_p1[p] = P1[r]; s_p2[p] = P2[r];
            }
        }
    }
    // zero tail param slots => padded k produce wgt = 1*0*1 = 0
    for (int idx = total + tid; idx < MAXL; idx += 512) {
        s_p0[idx] = make_float4(0,0,0,0);
        s_p1[idx] = make_float4(0,0,0,0);
        s_p2[idx] = make_float4(0,0,0,0);
    }
    __syncthreads();

    // ---- Per-chunk: stage A (feats) + B (wgt), then MFMA ----------------
    const int c15 = lane & 15, g = lane >> 4;

    f32x4 acc[4][2];   // [ch-tile][px-subtile], static indexing only
    #pragma unroll
    for (int a = 0; a < 4; ++a) {
        acc[a][0] = (f32x4){0.f,0.f,0.f,0.f};
        acc[a][1] = (f32x4){0.f,0.f,0.f,0.f};
    }

    float pxf[4], pyf[4];
    #pragma unroll
    for (int j = 0; j < 4; ++j) {
        const int px = j*64 + lane;
        pxf[j] = x0 + (px & 31) + 0.5f;
        pyf[j] = y0 + (px >> 5) + 0.5f;
    }

    for (int base = 0; base < total; base += 64) {
        const int rem = min(total - base, 64);
        const int nw  = (rem + 15) >> 4;     // k-window in 16-slot units

        // A-stage: A_lds[c][k] = softplus(fdc[list[k]][c]) as f16, 0-padded
        {
            const int c = tid & 63, kq = tid >> 6;   // kq in [0,8)
            for (int i = 0; i < nw; ++i) {
                const int k0 = i*16 + kq*2;
                float v0 = 0.f, v1 = 0.f;
                if (k0 < rem) {
                    const int n = (int)s_list[base + k0];
                    const float x = fdc[(n << 6) + c];
                    v0 = 0.69314718f * __builtin_amdgcn_logf(
                             1.f + __builtin_amdgcn_exp2f(L2E * x));
                }
                if (k0 + 1 < rem) {
                    const int n = (int)s_list[base + k0 + 1];
                    const float x = fdc[(n << 6) + c];
                    v1 = 0.69314718f * __builtin_amdgcn_logf(
                             1.f + __builtin_amdgcn_exp2f(L2E * x));
                }
                *(f16x2*)&A_lds[c][k0] = (f16x2){(_Float16)v0, (_Float16)v1};
            }
        }

        // B-stage: waves parallel over k; zeroed tail params give wgt = 0
        for (int i = 0; i < nw; ++i) {
            const int k0 = 2*(i*8 + w);
            const float4 p0a = s_p0[base+k0],   p1a = s_p1[base+k0],   p2a = s_p2[base+k0];
            const float4 p0b = s_p0[base+k0+1], p1b = s_p1[base+k0+1], p2b = s_p2[base+k0+1];
            #pragma unroll
            for (int j = 0; j < 4; ++j) {
                const float w0 = wgt_f(p0a, p1a, p2a, pxf[j], pyf[j]);
                const float w1 = wgt_f(p0b, p1b, p2b, pxf[j], pyf[j]);
                const int px = j*64 + lane;
                *(f16x2*)&B_lds[px][k0] = (f16x2){(_Float16)w0, (_Float16)w1};
            }
        }
        __syncthreads();

        // MFMA: wave w owns px-tiles {2w, 2w+1}, all 4 ch-tiles
        for (int kc = 0; kc < nw; ++kc) {
            const int kb = kc*16 + g*4;
            f16x4 af0 = *(const f16x4*)&A_lds[ 0 + c15][kb];
            f16x4 af1 = *(const f16x4*)&A_lds[16 + c15][kb];
            f16x4 af2 = *(const f16x4*)&A_lds[32 + c15][kb];
            f16x4 af3 = *(const f16x4*)&A_lds[48 + c15][kb];
            f16x4 bf0 = *(const f16x4*)&B_lds[(w*2+0)*16 + c15][kb];
            f16x4 bf1 = *(const f16x4*)&B_lds[(w*2+1)*16 + c15][kb];

            acc[0][0] = __builtin_amdgcn_mfma_f32_16x16x16f16(af0, bf0, acc[0][0], 0,0,0);
            acc[0][1] = __builtin_amdgcn_mfma_f32_16x16x16f16(af0, bf1, acc[0][1], 0,0,0);
            acc[1][0] = __builtin_amdgcn_mfma_f32_16x16x16f16(af1, bf0, acc[1][0], 0,0,0);
            acc[1][1] = __builtin_amdgcn_mfma_f32_16x16x16f16(af1, bf1, acc[1][1], 0,0,0);
            acc[2][0] = __builtin_amdgcn_mfma_f32_16x16x16f16(af2, bf0, acc[2][0], 0,0,0);
            acc[2][1] = __builtin_amdgcn_mfma_f32_16x16x16f16(af2, bf1, acc[2][1], 0,0,0);
            acc[3][0] = __builtin_amdgcn_mfma_f32_16x16x16f16(af3, bf0, acc[3][0], 0,0,0);
            acc[3][1] = __builtin_amdgcn_mfma_f32_16x16x16f16(af3, bf1, acc[3][1], 0,0,0);
        }
        if (base + 64 < total) __syncthreads();   // protect LDS for next chunk
    }

    // ---- Store: D frag (col=px: lane&15, row=ch: g*4+q), clipped ---------
    #pragma unroll
    for (int mt = 0; mt < 4; ++mt) {
        #pragma unroll
        for (int ntl = 0; ntl < 2; ++ntl) {
            const int px = (w*2 + ntl)*16 + c15;
            const int pg = ((y0 + (px >> 5)) << 8) + x0 + (px & 31);
            #pragma unroll
            for (int q = 0; q < 4; ++q) {
                const int ch = mt*16 + g*4 + q;
                out[(ch << 16) + pg] = fminf(fmaxf(acc[mt][ntl][q], 0.f), 1.f);
            }
        }
    }
}

// ---------------------------------------------------------------------------
extern "C" void kernel_launch(void* const* d_in, const int* in_sizes, int n_in,
                              void* d_out, int out_size, void* d_ws, size_t ws_size,
                              hipStream_t stream) {
    const float* xyz  = (const float*)d_in[0];
    const float* chol = (const float*)d_in[1];
    const float* opac = (const float*)d_in[2];
    const float* fdc  = (const float*)d_in[3];
    const float* gfrq = (const float*)d_in[4];
    const float* gwts = (const float*)d_in[5];

    fused_mfma_kernel<<<256, 512, 0, stream>>>(xyz, chol, opac, fdc,
                                               gfrq, gwts, (float*)d_out);
}

// Round 8
// 12.030 us; speedup vs baseline: 1.6444x; 1.0755x over previous
//
#include <hip/hip_runtime.h>
#include <hip/hip_bf16.h>

// Problem constants (fixed by the reference)
#define NG     1024
#define NC     64
#define CULL_T 15.0f   // cull when sigma > T; dropped mass <= ~4e-5
#define MAXL   256     // compacted live capacity (observed max ~45/tile)
#define APAD   258     // A_lds row stride (f16): 129 dwords -> stride-1 banks
#define L2E    1.44269504f
#define INV2PI 0.15915494f

typedef float    f32x4 __attribute__((ext_vector_type(4)));
typedef _Float16 f16x4 __attribute__((ext_vector_type(4)));
typedef _Float16 f16x2 __attribute__((ext_vector_type(2)));

// wgt for one (gaussian, pixel) pair. Coeffs pre-folded:
//  p0 = (xs, ys, na, nb), p1 = (nc, oK, wk0, wk1), p2 = freqs/2pi
//  exp2 arg = na*dx^2 + nb*dx*dy + nc*dy^2  (log2e and -0.5 folded in)
__device__ __forceinline__ float wgt_f(float4 p0, float4 p1, float4 p2,
                                       float pxf, float pyf) {
    const float dx = p0.x - pxf, dy = p0.y - pyf;
    const float t  = fmaf(p0.w, dy, p0.z * dx);
    const float s2 = fmaf(p1.x * dy, dy, dx * t);
    const float e  = __builtin_amdgcn_exp2f(s2);
    const float r1 = fmaf(p2.x, dx, p2.y * dy);
    const float c1 = __builtin_amdgcn_cosf(__builtin_amdgcn_fractf(r1));
    const float r2 = fmaf(p2.z, dx, p2.w * dy);
    const float c2 = __builtin_amdgcn_cosf(__builtin_amdgcn_fractf(r2));
    const float m  = fmaf(p1.w, c2, fmaf(p1.z, c1, 1.f));
    return e * p1.y * m;
}

// ---------------------------------------------------------------------------
// One 512-thread block (8 waves, 2/SIMD) per 32x8 pixel tile.
//  Phase A: light prep (cull geometry) for 2 gaussians/thread; heavy prep
//           (gabor/sigmoid) predicated on live; ballot-compact ascending
//           -> LDS params (zero tail). No B matrix in LDS at all.
//  Phase A2: softplus(feats)^T -> A_lds[c][k] (f16, all k in one pass).
//  Phase B: MFMA loop; B-fragments are computed DIRECTLY in registers:
//           lane (g,c15) of wave w evaluates wgt(k = kc*16+g*4+j,
//           px = 32w + 16*ntl + c15) for j=0..3, ntl=0..1 — each (k,px)
//           computed exactly once per block, zero LDS round-trip.
//  Store: D frags (col=px=lane&15, row=ch=(lane>>4)*4+q), nontemporal.
// ---------------------------------------------------------------------------
__global__ __launch_bounds__(512) void fused_mfma_kernel(
    const float* __restrict__ xyz,  const float* __restrict__ chol,
    const float* __restrict__ opac, const float* __restrict__ fdc,
    const float* __restrict__ gfrq, const float* __restrict__ gwts,
    float* __restrict__ out)
{
    __shared__ float4 s_p0[MAXL], s_p1[MAXL], s_p2[MAXL];   // 12 KB
    __shared__ unsigned short s_list[MAXL];
    __shared__ int s_scnt[16];
    __shared__ _Float16 A_lds[NC][APAD];                    // 33 KB feats^T

    const int tid  = threadIdx.x;
    const int lane = tid & 63, w = tid >> 6;   // 8 waves

    const int x0 = (blockIdx.x & 7) << 5;
    const int y0 = (blockIdx.x >> 3) << 3;
    const float xlo = x0 + 0.5f, xhi = x0 + 31.5f;
    const float ylo = y0 + 0.5f, yhi = y0 + 7.5f;

    // ---- Phase A: prep + cull, 2 gaussians per thread -------------------
    float4 P0[2];
    float  NCC[2], OK[2];
    bool   lv[2];
    int    pos[2];
    #pragma unroll
    for (int r = 0; r < 2; ++r) {
        const int n = (r << 9) + tid;        // r-major => ascending ids
        const float2 xy = ((const float2*)xyz)[n];
        // xs = 128*(tanh(x)+1) = 256 - 256/(1+exp2(2*log2e*x))
        const float ex = __builtin_amdgcn_exp2f(2.f * L2E * xy.x);
        const float ey = __builtin_amdgcn_exp2f(2.f * L2E * xy.y);
        const float xs = 256.f - 256.f * __builtin_amdgcn_rcpf(1.f + ex);
        const float ys = 256.f - 256.f * __builtin_amdgcn_rcpf(1.f + ey);

        const float l1 = chol[3*n]     + 0.5f;
        const float l2 = chol[3*n + 1];
        const float l3 = chol[3*n + 2] + 0.5f;
        const float s11 = l1*l1, s12 = l1*l2, s22 = l2*l2 + l3*l3;
        const float dt  = (l1*l3) * (l1*l3);
        const float inv = __builtin_amdgcn_rcpf(dt);
        const float na = -0.5f * L2E * s22 * inv;   // -0.5*ca*log2e
        const float nb =          L2E * s12 * inv;  // -cb*log2e
        const float nc = -0.5f * L2E * s11 * inv;
        const float mid = 0.5f * (s11 + s22);
        const float lam = mid + __builtin_amdgcn_sqrtf(fmaxf(mid*mid - dt, 1e-8f));
        const float radius = ceilf(3.f * __builtin_amdgcn_sqrtf(lam));
        const float keep = (radius > 1.0f) ? 1.f : 0.f;   // RADIUS_CLIP=1
        const float oK = opac[n] * keep;
        const float r2 = (oK != 0.f) ? (2.f * CULL_T * lam) : -1.f;

        const float nx = fminf(fmaxf(xs, xlo), xhi);
        const float ny = fminf(fmaxf(ys, ylo), yhi);
        const float ddx = xs - nx, ddy = ys - ny;
        lv[r] = (ddx*ddx + ddy*ddy) <= r2;

        const unsigned long long m = __ballot(lv[r]);
        pos[r] = __popcll(m & ((1ull << lane) - 1ull));
        if (lane == 0) s_scnt[(r << 3) + w] = __popcll(m);

        P0[r] = make_float4(xs, ys, na, nb);
        NCC[r] = nc; OK[r] = oK;
    }
    __syncthreads();

    int pre[17];
    pre[0] = 0;
    #pragma unroll
    for (int s = 0; s < 16; ++s) pre[s+1] = pre[s] + s_scnt[s];
    const int total = min(pre[16], MAXL);

    // heavy prep (gabor freq/weight trans ops) only for survivors
    #pragma unroll
    for (int r = 0; r < 2; ++r) {
        if (lv[r]) {
            const int p = pre[(r << 3) + w] + pos[r];
            if (p < MAXL) {
                const int n = (r << 9) + tid;
                const float4 gf = ((const float4*)gfrq)[n];
                const float2 gw = ((const float2*)gwts)[n];
                s_list[p] = (unsigned short)n;
                s_p0[p] = P0[r];
                s_p1[p] = make_float4(NCC[r], OK[r],
                    __builtin_amdgcn_rcpf(1.f + __builtin_amdgcn_exp2f(-L2E*gw.x)),
                    __builtin_amdgcn_rcpf(1.f + __builtin_amdgcn_exp2f(-L2E*gw.y)));
                s_p2[p] = make_float4(
                    __builtin_amdgcn_exp2f(L2E*gf.x)*INV2PI,
                    __builtin_amdgcn_exp2f(L2E*gf.y)*INV2PI,
                    __builtin_amdgcn_exp2f(L2E*gf.z)*INV2PI,
                    __builtin_amdgcn_exp2f(L2E*gf.w)*INV2PI);
            }
        }
    }
    // zero tail param slots => padded k produce wgt = 1*0*1 = 0
    for (int idx = total + tid; idx < MAXL; idx += 512) {
        s_p0[idx] = make_float4(0,0,0,0);
        s_p1[idx] = make_float4(0,0,0,0);
        s_p2[idx] = make_float4(0,0,0,0);
    }
    __syncthreads();

    const int nkc = (total + 15) >> 4;       // 16-k windows

    // ---- Phase A2: A_lds[c][k] = softplus(fdc[list[k]][c]) as f16 --------
    {
        const int c = tid & 63, kq = tid >> 6;   // kq in [0,8)
        for (int i = 0; i < nkc; ++i) {
            const int k0 = (i << 4) + (kq << 1);
            float v0 = 0.f, v1 = 0.f;
            if (k0 < total) {
                const int n = (int)s_list[k0];
                const float x = fdc[(n << 6) + c];
                v0 = 0.69314718f * __builtin_amdgcn_logf(
                         1.f + __builtin_amdgcn_exp2f(L2E * x));
            }
            if (k0 + 1 < total) {
                const int n = (int)s_list[k0 + 1];
                const float x = fdc[(n << 6) + c];
                v1 = 0.69314718f * __builtin_amdgcn_logf(
                         1.f + __builtin_amdgcn_exp2f(L2E * x));
            }
            *(f16x2*)&A_lds[c][k0] = (f16x2){(_Float16)v0, (_Float16)v1};
        }
    }
    __syncthreads();

    // ---- Phase B: MFMA with in-register B fragments ----------------------
    const int c15 = lane & 15, g = lane >> 4;
    const float pxf0 = x0 + c15 + 0.5f;         // px tile 2w   (cols 0..15)
    const float pxf1 = x0 + 16 + c15 + 0.5f;    // px tile 2w+1 (cols 16..31)
    const float pyf  = y0 + w + 0.5f;           // row = w

    f32x4 acc[4][2];   // [ch-tile][px-subtile]
    #pragma unroll
    for (int a = 0; a < 4; ++a) {
        acc[a][0] = (f32x4){0.f,0.f,0.f,0.f};
        acc[a][1] = (f32x4){0.f,0.f,0.f,0.f};
    }

    for (int kc = 0; kc < nkc; ++kc) {
        const int kb = (kc << 4) + (g << 2);    // this lane's 4 k values

        const float4 q00 = s_p0[kb],   q10 = s_p1[kb],   q20 = s_p2[kb];
        const float4 q01 = s_p0[kb+1], q11 = s_p1[kb+1], q21 = s_p2[kb+1];
        const float4 q02 = s_p0[kb+2], q12 = s_p1[kb+2], q22 = s_p2[kb+2];
        const float4 q03 = s_p0[kb+3], q13 = s_p1[kb+3], q23 = s_p2[kb+3];

        const f16x4 bf0 = {
            (_Float16)wgt_f(q00, q10, q20, pxf0, pyf),
            (_Float16)wgt_f(q01, q11, q21, pxf0, pyf),
            (_Float16)wgt_f(q02, q12, q22, pxf0, pyf),
            (_Float16)wgt_f(q03, q13, q23, pxf0, pyf) };
        const f16x4 bf1 = {
            (_Float16)wgt_f(q00, q10, q20, pxf1, pyf),
            (_Float16)wgt_f(q01, q11, q21, pxf1, pyf),
            (_Float16)wgt_f(q02, q12, q22, pxf1, pyf),
            (_Float16)wgt_f(q03, q13, q23, pxf1, pyf) };

        const f16x4 af0 = *(const f16x4*)&A_lds[ 0 + c15][kb];
        const f16x4 af1 = *(const f16x4*)&A_lds[16 + c15][kb];
        const f16x4 af2 = *(const f16x4*)&A_lds[32 + c15][kb];
        const f16x4 af3 = *(const f16x4*)&A_lds[48 + c15][kb];

        acc[0][0] = __builtin_amdgcn_mfma_f32_16x16x16f16(af0, bf0, acc[0][0], 0,0,0);
        acc[0][1] = __builtin_amdgcn_mfma_f32_16x16x16f16(af0, bf1, acc[0][1], 0,0,0);
        acc[1][0] = __builtin_amdgcn_mfma_f32_16x16x16f16(af1, bf0, acc[1][0], 0,0,0);
        acc[1][1] = __builtin_amdgcn_mfma_f32_16x16x16f16(af1, bf1, acc[1][1], 0,0,0);
        acc[2][0] = __builtin_amdgcn_mfma_f32_16x16x16f16(af2, bf0, acc[2][0], 0,0,0);
        acc[2][1] = __builtin_amdgcn_mfma_f32_16x16x16f16(af2, bf1, acc[2][1], 0,0,0);
        acc[3][0] = __builtin_amdgcn_mfma_f32_16x16x16f16(af3, bf0, acc[3][0], 0,0,0);
        acc[3][1] = __builtin_amdgcn_mfma_f32_16x16x16f16(af3, bf1, acc[3][1], 0,0,0);
    }

    // ---- Store: D frag (col=px: c15, row=ch: g*4+q), clipped, NT ---------
    const int pg0 = ((y0 + w) << 8) + x0 + c15;
    #pragma unroll
    for (int mt = 0; mt < 4; ++mt) {
        #pragma unroll
        for (int q = 0; q < 4; ++q) {
            const int ch = mt*16 + g*4 + q;
            __builtin_nontemporal_store(
                fminf(fmaxf(acc[mt][0][q], 0.f), 1.f), &out[(ch << 16) + pg0]);
            __builtin_nontemporal_store(
                fminf(fmaxf(acc[mt][1][q], 0.f), 1.f), &out[(ch << 16) + pg0 + 16]);
        }
    }
}

// ---------------------------------------------------------------------------
extern "C" void kernel_launch(void* const* d_in, const int* in_sizes, int n_in,
                              void* d_out, int out_size, void* d_ws, size_t ws_size,
                              hipStream_t stream) {
    const float* xyz  = (const float*)d_in[0];
    const float* chol = (const float*)d_in[1];
    const float* opac = (const float*)d_in[2];
    const float* fdc  = (const float*)d_in[3];
    const float* gfrq = (const float*)d_in[4];
    const float* gwts = (const float*)d_in[5];

    fused_mfma_kernel<<<256, 512, 0, stream>>>(xyz, chol, opac, fdc,
                                               gfrq, gwts, (float*)d_out);
}

// Round 9
// 11.301 us; speedup vs baseline: 1.7505x; 1.0645x over previous
//
#include <hip/hip_runtime.h>
#include <hip/hip_bf16.h>

// Problem constants (fixed by the reference)
#define NG     1024
#define NC     64
#define CULL_T 15.0f   // cull when sigma > T; dropped mass <= ~4e-5
#define MAXL   256     // compacted live capacity (observed max ~45/tile)
#define APAD   258     // A_lds row stride (f16): 129 dwords -> stride-1 banks
#define L2E    1.44269504f
#define INV2PI 0.15915494f

typedef float    f32x4 __attribute__((ext_vector_type(4)));
typedef _Float16 f16x4 __attribute__((ext_vector_type(4)));
typedef _Float16 f16x2 __attribute__((ext_vector_type(2)));

// wgt for one (gaussian, pixel) pair. Coeffs pre-folded:
//  p0 = (xs, ys, na, nb), p1 = (nc, oK, wk0, wk1), p2 = freqs/2pi
//  exp2 arg = na*dx^2 + nb*dx*dy + nc*dy^2  (log2e and -0.5 folded in)
__device__ __forceinline__ float wgt_f(float4 p0, float4 p1, float4 p2,
                                       float pxf, float pyf) {
    const float dx = p0.x - pxf, dy = p0.y - pyf;
    const float t  = fmaf(p0.w, dy, p0.z * dx);
    const float s2 = fmaf(p1.x * dy, dy, dx * t);
    const float e  = __builtin_amdgcn_exp2f(s2);
    const float r1 = fmaf(p2.x, dx, p2.y * dy);
    const float c1 = __builtin_amdgcn_cosf(__builtin_amdgcn_fractf(r1));
    const float r2 = fmaf(p2.z, dx, p2.w * dy);
    const float c2 = __builtin_amdgcn_cosf(__builtin_amdgcn_fractf(r2));
    const float m  = fmaf(p1.w, c2, fmaf(p1.z, c1, 1.f));
    return e * p1.y * m;
}

// ---------------------------------------------------------------------------
// One 1024-thread block (16 waves = 4 waves/SIMD) per 32x8 pixel tile.
//  Phase A: prep 1 gaussian/thread (HW-op math), cull, ballot-compact
//           ascending -> LDS params (zero tail); heavy prep only for live.
//  Phase A2: softplus(feats)^T -> A_lds[c][k], one k-slot per thread/window.
//  Phase B: MFMA; B-fragments computed directly in registers: wave w owns
//           px-tile w (16 px), lane (g,c15) evaluates wgt for k=kc*16+g*4+j.
//           Each (k,px) pair computed exactly once per block.
//  Store: D frags (col=px=lane&15, row=ch=(lane>>4)*4+q), nontemporal.
// ---------------------------------------------------------------------------
__global__ __launch_bounds__(1024) void fused_mfma_kernel(
    const float* __restrict__ xyz,  const float* __restrict__ chol,
    const float* __restrict__ opac, const float* __restrict__ fdc,
    const float* __restrict__ gfrq, const float* __restrict__ gwts,
    float* __restrict__ out)
{
    __shared__ float4 s_p0[MAXL], s_p1[MAXL], s_p2[MAXL];   // 12 KB
    __shared__ unsigned short s_list[MAXL];
    __shared__ int s_scnt[16];
    __shared__ _Float16 A_lds[NC][APAD];                    // 33 KB feats^T

    const int tid  = threadIdx.x;
    const int lane = tid & 63, w = tid >> 6;   // 16 waves

    const int x0 = (blockIdx.x & 7) << 5;
    const int y0 = (blockIdx.x >> 3) << 3;
    const float xlo = x0 + 0.5f, xhi = x0 + 31.5f;
    const float ylo = y0 + 0.5f, yhi = y0 + 7.5f;

    // ---- Phase A: prep + cull, 1 gaussian per thread --------------------
    const int n = tid;
    const float2 xy = ((const float2*)xyz)[n];
    // xs = 128*(tanh(x)+1) = 256 - 256/(1+exp2(2*log2e*x))
    const float ex = __builtin_amdgcn_exp2f(2.f * L2E * xy.x);
    const float ey = __builtin_amdgcn_exp2f(2.f * L2E * xy.y);
    const float xs = 256.f - 256.f * __builtin_amdgcn_rcpf(1.f + ex);
    const float ys = 256.f - 256.f * __builtin_amdgcn_rcpf(1.f + ey);

    const float l1 = chol[3*n]     + 0.5f;
    const float l2 = chol[3*n + 1];
    const float l3 = chol[3*n + 2] + 0.5f;
    const float s11 = l1*l1, s12 = l1*l2, s22 = l2*l2 + l3*l3;
    const float dt  = (l1*l3) * (l1*l3);
    const float inv = __builtin_amdgcn_rcpf(dt);
    const float na = -0.5f * L2E * s22 * inv;   // -0.5*ca*log2e
    const float nb =          L2E * s12 * inv;  // -cb*log2e
    const float ncc = -0.5f * L2E * s11 * inv;
    const float mid = 0.5f * (s11 + s22);
    const float lam = mid + __builtin_amdgcn_sqrtf(fmaxf(mid*mid - dt, 1e-8f));
    const float radius = ceilf(3.f * __builtin_amdgcn_sqrtf(lam));
    const float keep = (radius > 1.0f) ? 1.f : 0.f;   // RADIUS_CLIP=1
    const float oK = opac[n] * keep;
    const float r2 = (oK != 0.f) ? (2.f * CULL_T * lam) : -1.f;

    const float nx = fminf(fmaxf(xs, xlo), xhi);
    const float ny = fminf(fmaxf(ys, ylo), yhi);
    const float ddx = xs - nx, ddy = ys - ny;
    const bool lv = (ddx*ddx + ddy*ddy) <= r2;

    const unsigned long long m = __ballot(lv);
    const int pos = __popcll(m & ((1ull << lane) - 1ull));
    if (lane == 0) s_scnt[w] = __popcll(m);
    __syncthreads();

    int pre[17];
    pre[0] = 0;
    #pragma unroll
    for (int s = 0; s < 16; ++s) pre[s+1] = pre[s] + s_scnt[s];
    const int total = min(pre[16], MAXL);

    // heavy prep (gabor freq/weight trans ops) only for survivors
    if (lv) {
        const int p = pre[w] + pos;
        if (p < MAXL) {
            const float4 gf = ((const float4*)gfrq)[n];
            const float2 gw = ((const float2*)gwts)[n];
            s_list[p] = (unsigned short)n;
            s_p0[p] = make_float4(xs, ys, na, nb);
            s_p1[p] = make_float4(ncc, oK,
                __builtin_amdgcn_rcpf(1.f + __builtin_amdgcn_exp2f(-L2E*gw.x)),
                __builtin_amdgcn_rcpf(1.f + __builtin_amdgcn_exp2f(-L2E*gw.y)));
            s_p2[p] = make_float4(
                __builtin_amdgcn_exp2f(L2E*gf.x)*INV2PI,
                __builtin_amdgcn_exp2f(L2E*gf.y)*INV2PI,
                __builtin_amdgcn_exp2f(L2E*gf.z)*INV2PI,
                __builtin_amdgcn_exp2f(L2E*gf.w)*INV2PI);
        }
    }
    // zero tail param slots => padded k produce wgt = 1*0*1 = 0
    for (int idx = total + tid; idx < MAXL; idx += 1024) {
        s_p0[idx] = make_float4(0,0,0,0);
        s_p1[idx] = make_float4(0,0,0,0);
        s_p2[idx] = make_float4(0,0,0,0);
    }
    __syncthreads();

    const int nkc = (total + 15) >> 4;       // 16-k windows

    // ---- Phase A2: A_lds[c][k] = softplus(fdc[list[k]][c]) as f16 --------
    {
        const int c = tid & 63, kq = tid >> 6;   // kq in [0,16)
        for (int i = 0; i < nkc; ++i) {
            const int k0 = (i << 4) + kq;
            float v0 = 0.f;
            if (k0 < total) {
                const int nn = (int)s_list[k0];
                const float x = fdc[(nn << 6) + c];
                v0 = 0.69314718f * __builtin_amdgcn_logf(
                         1.f + __builtin_amdgcn_exp2f(L2E * x));
            }
            A_lds[c][k0] = (_Float16)v0;
        }
    }
    __syncthreads();

    // ---- Phase B: MFMA with in-register B fragments ----------------------
    // wave w owns px-tile w: px = 16w + c15; col = (w&1)*16 + c15, row = w>>1
    const int c15 = lane & 15, g = lane >> 4;
    const float pxf = x0 + ((w & 1) << 4) + c15 + 0.5f;
    const float pyf = y0 + (w >> 1) + 0.5f;

    f32x4 acc[4];   // [ch-tile]
    #pragma unroll
    for (int a = 0; a < 4; ++a) acc[a] = (f32x4){0.f,0.f,0.f,0.f};

    for (int kc = 0; kc < nkc; ++kc) {
        const int kb = (kc << 4) + (g << 2);    // this lane's 4 k values

        const float4 q00 = s_p0[kb],   q10 = s_p1[kb],   q20 = s_p2[kb];
        const float4 q01 = s_p0[kb+1], q11 = s_p1[kb+1], q21 = s_p2[kb+1];
        const float4 q02 = s_p0[kb+2], q12 = s_p1[kb+2], q22 = s_p2[kb+2];
        const float4 q03 = s_p0[kb+3], q13 = s_p1[kb+3], q23 = s_p2[kb+3];

        const f16x4 bf = {
            (_Float16)wgt_f(q00, q10, q20, pxf, pyf),
            (_Float16)wgt_f(q01, q11, q21, pxf, pyf),
            (_Float16)wgt_f(q02, q12, q22, pxf, pyf),
            (_Float16)wgt_f(q03, q13, q23, pxf, pyf) };

        const f16x4 af0 = *(const f16x4*)&A_lds[ 0 + c15][kb];
        const f16x4 af1 = *(const f16x4*)&A_lds[16 + c15][kb];
        const f16x4 af2 = *(const f16x4*)&A_lds[32 + c15][kb];
        const f16x4 af3 = *(const f16x4*)&A_lds[48 + c15][kb];

        acc[0] = __builtin_amdgcn_mfma_f32_16x16x16f16(af0, bf, acc[0], 0,0,0);
        acc[1] = __builtin_amdgcn_mfma_f32_16x16x16f16(af1, bf, acc[1], 0,0,0);
        acc[2] = __builtin_amdgcn_mfma_f32_16x16x16f16(af2, bf, acc[2], 0,0,0);
        acc[3] = __builtin_amdgcn_mfma_f32_16x16x16f16(af3, bf, acc[3], 0,0,0);
    }

    // ---- Store: D frag (col=px: c15, row=ch: g*4+q), clipped, NT ---------
    const int pg = ((y0 + (w >> 1)) << 8) + x0 + ((w & 1) << 4) + c15;
    #pragma unroll
    for (int mt = 0; mt < 4; ++mt) {
        #pragma unroll
        for (int q = 0; q < 4; ++q) {
            const int ch = mt*16 + g*4 + q;
            __builtin_nontemporal_store(
                fminf(fmaxf(acc[mt][q], 0.f), 1.f), &out[(ch << 16) + pg]);
        }
    }
}

// ---------------------------------------------------------------------------
extern "C" void kernel_launch(void* const* d_in, const int* in_sizes, int n_in,
                              void* d_out, int out_size, void* d_ws, size_t ws_size,
                              hipStream_t stream) {
    const float* xyz  = (const float*)d_in[0];
    const float* chol = (const float*)d_in[1];
    const float* opac = (const float*)d_in[2];
    const float* fdc  = (const float*)d_in[3];
    const float* gfrq = (const float*)d_in[4];
    const float* gwts = (const float*)d_in[5];

    fused_mfma_kernel<<<256, 1024, 0, stream>>>(xyz, chol, opac, fdc,
                                                gfrq, gwts, (float*)d_out);
}